// Round 8
// baseline (721.393 us; speedup 1.0000x reference)
//
#include <hip/hip_runtime.h>
#include <hip/hip_bf16.h>

// JointNet: out[b,t,u,:] = tanh(enc@w1a [bt] + dec@w1b [bu] + b1) @ w2 + b2
// B=4 T=256 U=64 D=640 INNER=640 V=1024;  M = B*T*U = 65536
//
// DIAGNOSTIC ROUND v2 (rounds 5-7 lost to infra): jgemm256d runs its 20-tile
// K-pipeline FOUR times (1 real + 3 sunk).
//  - pass 1 stores the real output (bit-identical to round 4)
//  - passes 2-4 re-run the identical pipeline; acc kept live via asm sinks
// => t_jcore = (dur_us - 457.6)/3, and the jgemm dispatch exceeds the ~197us
//    harness fills under ALL theories -> its rocprof counters become visible.

typedef __attribute__((ext_vector_type(4))) float  f32x4;
typedef __attribute__((ext_vector_type(8))) __bf16 bf16x8;
typedef __attribute__((ext_vector_type(8))) unsigned short us8;

#define INNER 640
#define VOCAB 1024
#define M_TOT 65536   // 4*256*64
#define RE 1024       // B*T rows of encp
#define RD 256        // B*U rows of decp

// ws layout (bytes)
#define ENCP_B (RE * INNER * 4)                 // 2,621,440
#define DECP_B (RD * INNER * 4)                 //   655,360
#define W2BT_B (VOCAB * INNER * 2)              // 1,310,720
#define HB_B   ((size_t)M_TOT * INNER * 2)      // 83,886,080
#define OFF_DECP ((size_t)ENCP_B)
#define OFF_W2BT (OFF_DECP + DECP_B)
#define OFF_HB   (OFF_W2BT + W2BT_B)
#define NEED_FULL (OFF_HB + HB_B)

__device__ __forceinline__ unsigned short f2bf(float f) {
    unsigned int u = __float_as_uint(f);
    u = (u + 0x7FFFu + ((u >> 16) & 1u)) >> 16;   // round-to-nearest-even
    return (unsigned short)u;
}

__device__ __forceinline__ float fast_tanh(float x) {
    float e = __builtin_amdgcn_exp2f(x * 2.8853900817779268f);
    return 1.0f - 2.0f * __builtin_amdgcn_rcpf(e + 1.0f);
}

__device__ __forceinline__ void gl_lds16(const void* g, void* l) {
    __builtin_amdgcn_global_load_lds(
        (__attribute__((address_space(1))) void*)g,
        (__attribute__((address_space(3))) void*)l, 16, 0, 0);
}

// ---------------- prep: proj GEMMs (blocks 0..199) + w2 transpose/cast (200..359) --------
__global__ __launch_bounds__(256) void prep_kernel(
        const float* __restrict__ enc, const float* __restrict__ dec,
        const float* __restrict__ w1, const float* __restrict__ b1,
        const float* __restrict__ w2,
        float* __restrict__ encp, float* __restrict__ decp,
        unsigned short* __restrict__ w2bT) {
    __shared__ __align__(16) char smem[64 * 65 * 4];
    int bx = blockIdx.x;
    int t = threadIdx.x;
    if (bx < 200) {
        float (*At)[68] = (float(*)[68])smem;
        float (*Bt)[68] = (float(*)[68])(smem + 16 * 68 * 4);
        const float* Ap; float* Op; const float* Wp; int mt, nt; bool isdec;
        if (bx < 160) { isdec = false; mt = bx / 10; nt = bx % 10; Ap = enc; Op = encp; Wp = w1; }
        else { isdec = true; int i = bx - 160; mt = i / 10; nt = i % 10; Ap = dec; Op = decp; Wp = w1 + 640 * 640; }
        int m0 = mt * 64, n0 = nt * 64;
        int tx = t & 15, ty = t >> 4;
        int ar = t >> 2, ac = t & 3;
        int br = t >> 4, bc = t & 15;
        float acc[4][4] = {};
        for (int k0 = 0; k0 < 640; k0 += 16) {
            f32x4 av = *(const f32x4*)&Ap[(m0 + ar) * 640 + k0 + ac * 4];
            f32x4 bv = *(const f32x4*)&Wp[(k0 + br) * 640 + n0 + bc * 4];
            __syncthreads();
            At[ac * 4 + 0][ar] = av[0]; At[ac * 4 + 1][ar] = av[1];
            At[ac * 4 + 2][ar] = av[2]; At[ac * 4 + 3][ar] = av[3];
            *(f32x4*)&Bt[br][bc * 4] = bv;
            __syncthreads();
            #pragma unroll
            for (int kk = 0; kk < 16; ++kk) {
                f32x4 a = *(const f32x4*)&At[kk][ty * 4];
                f32x4 b = *(const f32x4*)&Bt[kk][tx * 4];
                #pragma unroll
                for (int i = 0; i < 4; ++i)
                    #pragma unroll
                    for (int j = 0; j < 4; ++j)
                        acc[i][j] += a[i] * b[j];
            }
        }
        f32x4 bias = {0.f, 0.f, 0.f, 0.f};
        if (isdec) bias = *(const f32x4*)&b1[n0 + tx * 4];
        #pragma unroll
        for (int i = 0; i < 4; ++i) {
            f32x4 o;
            #pragma unroll
            for (int j = 0; j < 4; ++j) o[j] = acc[i][j] + bias[j];
            *(f32x4*)&Op[(m0 + ty * 4 + i) * 640 + n0 + tx * 4] = o;
        }
    } else {
        float (*tile)[65] = (float(*)[65])smem;
        int i = bx - 200;
        int kt = i % 10, ntc = i / 10;
        int k0 = kt * 64, n0 = ntc * 64;
        #pragma unroll
        for (int p = 0; p < 4; ++p) {
            int id = t + p * 256;
            int r = id >> 4, c4 = id & 15;
            f32x4 v = *(const f32x4*)&w2[(k0 + r) * 1024 + n0 + c4 * 4];
            tile[r][c4 * 4 + 0] = v[0]; tile[r][c4 * 4 + 1] = v[1];
            tile[r][c4 * 4 + 2] = v[2]; tile[r][c4 * 4 + 3] = v[3];
        }
        __syncthreads();
        #pragma unroll
        for (int p = 0; p < 2; ++p) {
            int id = t + p * 256;
            int n = id >> 3, ch = id & 7;
            us8 hv;
            #pragma unroll
            for (int q = 0; q < 8; ++q) hv[q] = f2bf(tile[ch * 8 + q][n]);
            *(us8*)&w2bT[(n0 + n) * 640 + k0 + ch * 8] = hv;
        }
    }
}

// ---------------- hmat: Hb = bf16(tanh(encp + decp)) ----------------
__global__ __launch_bounds__(256) void hmat_kernel(
        const float* __restrict__ encp, const float* __restrict__ decp,
        unsigned short* __restrict__ Hb) {
    int c = blockIdx.x * 256 + threadIdx.x;
    int m = c / 80;
    int kc = (c - m * 80) * 8;
    int r1 = m >> 6;
    int r2 = ((m >> 14) << 6) | (m & 63);
    const float* ep = encp + r1 * 640 + kc;
    const float* dp = decp + r2 * 640 + kc;
    f32x4 e0 = *(const f32x4*)ep, e1 = *(const f32x4*)(ep + 4);
    f32x4 d0 = *(const f32x4*)dp, d1 = *(const f32x4*)(dp + 4);
    us8 hv;
    #pragma unroll
    for (int q = 0; q < 4; ++q) hv[q] = f2bf(fast_tanh(e0[q] + d0[q]));
    #pragma unroll
    for (int q = 0; q < 4; ++q) hv[4 + q] = f2bf(fast_tanh(e1[q] + d1[q]));
    *(us8*)&Hb[(size_t)m * 640 + kc] = hv;
}

// ---------------- jgemm256d: round-4 kernel, K-pipeline run 4x (diagnostic) --------
__global__ __launch_bounds__(512, 2) void jgemm256d_kernel(
        const unsigned short* __restrict__ Hb, const unsigned short* __restrict__ w2bT,
        const float* __restrict__ b2, float* __restrict__ out) {
    __shared__ __align__(16) unsigned short sA[4][256 * 32];
    __shared__ __align__(16) unsigned short sB[4][256 * 32];
    int bx = blockIdx.x;
    int lb = ((bx & 7) << 7) | (bx >> 3);   // XCD-chunked bijective swizzle
    int nt = lb & 3, mt = lb >> 2;
    int m0 = mt << 8, n0 = nt << 8;
    int tid = threadIdx.x;
    int lane = tid & 63, wave = tid >> 6;
    int wm = wave >> 2, wn = wave & 3;

    const char* HbBase = (const char*)Hb + (size_t)(m0 + (tid >> 2)) * 1280 + (tid & 3) * 16;
    const char* WbBase = (const char*)w2bT + (size_t)(n0 + (tid >> 2)) * 1280 + (tid & 3) * 16;

    f32x4 acc[8][4] = {};
    int fr = lane & 15, fk8 = (lane >> 4) << 3;
    int arow0 = (wm << 7) + fr;
    int brow0 = (wn << 6) + fr;

#define STAGE_TILE(tt) do { \
    unsigned short* As_ = sA[(tt) & 3]; unsigned short* Bs_ = sB[(tt) & 3]; \
    const char* ga_ = HbBase + (tt) * 64; \
    const char* gb_ = WbBase + (tt) * 64; \
    gl_lds16(ga_,          (void*)(As_ + wave * 512)); \
    gl_lds16(ga_ + 163840, (void*)(As_ + 4096 + wave * 512)); \
    gl_lds16(gb_,          (void*)(Bs_ + wave * 512)); \
    gl_lds16(gb_ + 163840, (void*)(Bs_ + 4096 + wave * 512)); \
} while (0)

#define JTILE(t_, VN_, DOST_) do { \
    asm volatile("s_waitcnt vmcnt(%0)" :: "i"(VN_) : "memory"); \
    __builtin_amdgcn_s_barrier(); \
    __builtin_amdgcn_sched_barrier(0); \
    if (DOST_) STAGE_TILE((t_) + 3); \
    const unsigned short* As_r = sA[(t_) & 3]; \
    const unsigned short* Bs_r = sB[(t_) & 3]; \
    bf16x8 af[8], bfv[4]; \
    _Pragma("unroll") for (int ri = 0; ri < 8; ++ri) \
        af[ri] = *(const bf16x8*)&As_r[(arow0 + ri * 16) * 32 + fk8]; \
    _Pragma("unroll") for (int ci = 0; ci < 4; ++ci) \
        bfv[ci] = *(const bf16x8*)&Bs_r[(brow0 + ci * 16) * 32 + fk8]; \
    __builtin_amdgcn_s_setprio(1); \
    _Pragma("unroll") for (int ri = 0; ri < 8; ++ri) \
        _Pragma("unroll") for (int ci = 0; ci < 4; ++ci) \
            acc[ri][ci] = __builtin_amdgcn_mfma_f32_16x16x32_bf16(af[ri], bfv[ci], acc[ri][ci], 0, 0, 0); \
    __builtin_amdgcn_s_setprio(0); \
} while (0)

    // ---- pass 1 (real) ----
    STAGE_TILE(0); STAGE_TILE(1); STAGE_TILE(2);
    for (int t = 0; t < 17; ++t) JTILE(t, 8, true);
    JTILE(17, 8, false);
    JTILE(18, 4, false);
    JTILE(19, 0, false);

    // epilogue: store REAL result now (bit-identical to round 4)
    {
        int crow = (lane >> 4) << 2;
        #pragma unroll
        for (int ci = 0; ci < 4; ++ci) {
            int col = n0 + (wn << 6) + ci * 16 + fr;
            float bb = b2[col];
            #pragma unroll
            for (int ri = 0; ri < 8; ++ri) {
                int row = m0 + (wm << 7) + ri * 16 + crow;
                #pragma unroll
                for (int r = 0; r < 4; ++r)
                    out[(size_t)(row + r) * 1024 + col] = acc[ri][ci][r] + bb;
            }
        }
    }

    // ---- passes 2-4 (timing X-ray; results sunk, never stored) ----
    // Safety at pass boundary: final JTILE drains vmcnt(0) before its barrier,
    // and restaged buffers 0-2 had their last readers >=3 barriers earlier.
    asm volatile("s_waitcnt vmcnt(0)" ::: "memory");
    __builtin_amdgcn_s_barrier();
    #pragma unroll 1
    for (int p = 0; p < 3; ++p) {
        STAGE_TILE(0); STAGE_TILE(1); STAGE_TILE(2);
        for (int t = 0; t < 17; ++t) JTILE(t, 8, true);
        JTILE(17, 8, false);
        JTILE(18, 4, false);
        JTILE(19, 0, false);
    }

#undef JTILE
#undef STAGE_TILE

    // keep pass 2-4 MFMAs alive (rule #17: anti-DCE sinks, scalar "v" operands)
    #pragma unroll
    for (int ri = 0; ri < 8; ++ri)
        #pragma unroll
        for (int ci = 0; ci < 4; ++ci)
            asm volatile("" :: "v"(acc[ri][ci][0]), "v"(acc[ri][ci][1]),
                              "v"(acc[ri][ci][2]), "v"(acc[ri][ci][3]));
}

// ---------------- fallback (small ws): old 128x128 fused kernel ----------------
__global__ __launch_bounds__(256) void jgemm_fused_kernel(
        const unsigned short* __restrict__ w2bT,
        const float* __restrict__ encp, const float* __restrict__ decp,
        const float* __restrict__ b2, float* __restrict__ out) {
    __shared__ __align__(16) unsigned short As[128 * 32];
    __shared__ __align__(16) unsigned short Bs[128 * 32];
    int bx = blockIdx.x;
    int lb = ((bx & 7) << 9) | (bx >> 3);
    int nt = lb & 7, mt = lb >> 3;
    int m0 = mt << 7, n0 = nt << 7;
    int tid = threadIdx.x;
    int lane = tid & 63, wave = tid >> 6;
    int wr = (wave >> 1) * 64, wc = (wave & 1) * 64;
    f32x4 acc[4][4] = {};
    int fr = lane & 15, fk = (lane >> 4) << 3;
    for (int kt = 0; kt < 20; ++kt) {
        int k0 = kt << 5;
        __syncthreads();
        int row = tid >> 1, kh = tid & 1;
        int m = m0 + row;
        int r1g = m >> 6;
        int r2g = ((m >> 14) << 6) | (m & 63);
        const float* ep = encp + r1g * 640 + k0 + kh * 16;
        const float* dp = decp + r2g * 640 + k0 + kh * 16;
        f32x4 e0 = *(const f32x4*)ep,       e1 = *(const f32x4*)(ep + 4);
        f32x4 e2 = *(const f32x4*)(ep + 8), e3 = *(const f32x4*)(ep + 12);
        f32x4 q0 = *(const f32x4*)dp,       q1 = *(const f32x4*)(dp + 4);
        f32x4 q2 = *(const f32x4*)(dp + 8), q3 = *(const f32x4*)(dp + 12);
        us8 h0, h1;
        #pragma unroll
        for (int q = 0; q < 4; ++q) {
            h0[q]     = f2bf(fast_tanh(e0[q] + q0[q]));
            h0[4 + q] = f2bf(fast_tanh(e1[q] + q1[q]));
            h1[q]     = f2bf(fast_tanh(e2[q] + q2[q]));
            h1[4 + q] = f2bf(fast_tanh(e3[q] + q3[q]));
        }
        *(us8*)&As[row * 32 + kh * 16] = h0;
        *(us8*)&As[row * 32 + kh * 16 + 8] = h1;
        #pragma unroll
        for (int j = 0; j < 2; ++j) {
            int srow = wave * 32 + j * 16 + (lane >> 2);
            const char* bg = (const char*)w2bT + (size_t)(n0 + srow) * 1280 + k0 * 2 + (lane & 3) * 16;
            gl_lds16(bg, (void*)&Bs[(wave * 32 + j * 16) * 32]);
        }
        __syncthreads();
        bf16x8 af[4], bf[4];
        #pragma unroll
        for (int i = 0; i < 4; ++i) {
            af[i] = *(const bf16x8*)&As[(wr + i * 16 + fr) * 32 + fk];
            bf[i] = *(const bf16x8*)&Bs[(wc + i * 16 + fr) * 32 + fk];
        }
        #pragma unroll
        for (int i = 0; i < 4; ++i)
            #pragma unroll
            for (int j = 0; j < 4; ++j)
                acc[i][j] = __builtin_amdgcn_mfma_f32_16x16x32_bf16(af[i], bf[j], acc[i][j], 0, 0, 0);
    }
    int ccol = lane & 15, crow = (lane >> 4) << 2;
    #pragma unroll
    for (int j = 0; j < 4; ++j) {
        int col = n0 + wc + j * 16 + ccol;
        float bb = b2[col];
        #pragma unroll
        for (int i = 0; i < 4; ++i) {
            int row = m0 + wr + i * 16 + crow;
            #pragma unroll
            for (int r = 0; r < 4; ++r)
                out[(size_t)(row + r) * 1024 + col] = acc[i][j][r] + bb;
        }
    }
}

extern "C" void kernel_launch(void* const* d_in, const int* in_sizes, int n_in,
                              void* d_out, int out_size, void* d_ws, size_t ws_size,
                              hipStream_t stream) {
    const float* enc = (const float*)d_in[0];
    const float* dec = (const float*)d_in[1];
    const float* w1  = (const float*)d_in[2];
    const float* b1  = (const float*)d_in[3];
    const float* w2  = (const float*)d_in[4];
    const float* b2  = (const float*)d_in[5];
    float* out = (float*)d_out;

    char* w = (char*)d_ws;
    float* encp = (float*)w;
    float* decp = (float*)(w + OFF_DECP);
    unsigned short* w2bT = (unsigned short*)(w + OFF_W2BT);
    unsigned short* Hb = (unsigned short*)(w + OFF_HB);

    prep_kernel<<<360, 256, 0, stream>>>(enc, dec, w1, b1, w2, encp, decp, w2bT);
    if (ws_size >= NEED_FULL) {
        hmat_kernel<<<20480, 256, 0, stream>>>(encp, decp, Hb);
        jgemm256d_kernel<<<1024, 512, 0, stream>>>(Hb, w2bT, b2, out);
    } else {
        jgemm_fused_kernel<<<4096, 256, 0, stream>>>(w2bT, encp, decp, b2, out);
    }
}